// Round 15
// baseline (312.419 us; speedup 1.0000x reference)
//
#include <hip/hip_runtime.h>
#include <hip/hip_bf16.h>
#include <stdint.h>

typedef __bf16 bf16;
typedef __bf16 bf16x8 __attribute__((ext_vector_type(8)));
typedef float f32x4 __attribute__((ext_vector_type(4)));

#define TAU (1.0f/30.0f)

#define NB 32
#define CI 256
#define CO 256
#define HH 64
#define WW 64
#define HID 64

// wn fragment-linear layout: [n][c(8 ci-chunks)][kk(9)][cbg(16)][lane(64)][j(8)]
#define WN_ELEMS ((size_t)NB*8*9*16*512)
#define WN_BYTES (WN_ELEMS*2)
// xb packed layout: [n][cg(32 ci-groups of 8)][h(64)][w(64)][j(8)] bf16
#define XB_ELEMS ((size_t)NB*32*64*64*8)
#define XB_BYTES (XB_ELEMS*2)

__device__ __forceinline__ void async16(void* lds_uniform_base, const void* g_perlane) {
  __builtin_amdgcn_global_load_lds(
      (const __attribute__((address_space(1))) uint32_t*)g_perlane,
      (__attribute__((address_space(3))) uint32_t*)lds_uniform_base, 16, 0, 0);
}

// Fused fp32->bf16 repack + global average pool (scalar loads: BW-bound;
// R13 showed float4+select packing regresses VALU).
__global__ void cvt_pool_kernel(const float* __restrict__ x, bf16* __restrict__ xb,
                                float* __restrict__ pooled) {
  const int cg = blockIdx.x, n = blockIdx.y, tid = threadIdx.x;
  const float* base = x + ((size_t)n*CI + cg*8)*4096;
  bf16* ob = xb + ((size_t)n*32 + cg)*4096*8;
  float s[8];
#pragma unroll
  for (int j = 0; j < 8; ++j) s[j] = 0.f;
  for (int it = 0; it < 16; ++it) {
    int pos = it*256 + tid;
    bf16x8 o;
#pragma unroll
    for (int j = 0; j < 8; ++j) {
      float v = base[(size_t)j*4096 + pos];
      s[j] += v;
      o[j] = (bf16)v;
    }
    *(bf16x8*)(ob + (size_t)pos*8) = o;
  }
  __shared__ float red[4][8];
#pragma unroll
  for (int j = 0; j < 8; ++j)
#pragma unroll
    for (int off = 32; off; off >>= 1) s[j] += __shfl_xor(s[j], off);
  int wv = tid >> 6, lane = tid & 63;
  if (lane == 0)
#pragma unroll
    for (int j = 0; j < 8; ++j) red[wv][j] = s[j];
  __syncthreads();
  if (tid < 8) {
    float t = red[0][tid] + red[1][tid] + red[2][tid] + red[3][tid];
    pooled[n*CI + cg*8 + tid] = t * (1.0f/4096.0f);
  }
}

// agg + inlined attention MLP. Each wave computes pi for 8 samples in-register
// (lane = hidden unit; width-64 shuffle reduce for the 4 logits), stashes in LDS;
// block 0 also writes pi to memory for conv's bias path.
__global__ void agg_kernel(const float* __restrict__ Wbank, const float* __restrict__ pooled,
                           const float* __restrict__ w1, const float* __restrict__ b1,
                           const float* __restrict__ w2, const float* __restrict__ b2,
                           float* __restrict__ pi_out, bf16* __restrict__ wn) {
  const int tid = threadIdx.x;
  const int wv = tid >> 6, lane = tid & 63;
  __shared__ float pi_l[NB][4];

  // --- attention: wave wv handles n = wv*8 .. wv*8+7 ---
  for (int i = 0; i < 8; ++i) {
    const int n = wv*8 + i;
    const float* pr = pooled + n*CI;
    float s = b1[lane];
    for (int c = 0; c < CI; ++c) s += pr[c] * w1[lane*CI + c];
    float hm = s > 0.f ? s : 0.f;
    float lg[4];
#pragma unroll
    for (int m = 0; m < 4; ++m) {
      float r = hm * w2[m*HID + lane];
#pragma unroll
      for (int off = 32; off; off >>= 1) r += __shfl_xor(r, off);
      lg[m] = r + b2[m];
    }
    if (lane == 0) {
      float l0 = lg[0]*TAU, l1 = lg[1]*TAU, l2 = lg[2]*TAU, l3 = lg[3]*TAU;
      float mx = fmaxf(fmaxf(l0, l1), fmaxf(l2, l3));
      float e0 = expf(l0-mx), e1 = expf(l1-mx), e2 = expf(l2-mx), e3 = expf(l3-mx);
      float inv = 1.f / (e0+e1+e2+e3);
      pi_l[n][0] = e0*inv; pi_l[n][1] = e1*inv; pi_l[n][2] = e2*inv; pi_l[n][3] = e3*inv;
    }
  }
  __syncthreads();
  if (blockIdx.x == 0 && tid < NB*4) pi_out[tid] = pi_l[tid >> 2][tid & 3];

  // --- aggregation (unchanged math; pi from LDS) ---
  int wid = blockIdx.x * 4 + wv;                   // 0..1151
  int c = wid / 144;
  int rem = wid - c*144;
  int kk = rem >> 4;
  int cbg = rem & 15;
  int co  = cbg*16 + (lane & 15);
  int ci0 = c*32 + (lane >> 4)*8;
  float w[4][8];
#pragma unroll
  for (int m = 0; m < 4; ++m)
#pragma unroll
    for (int j = 0; j < 8; ++j)
      w[m][j] = Wbank[(size_t)((co*4 + m)*256 + ci0 + j)*9 + kk];
  for (int n = 0; n < NB; ++n) {
    float p0 = pi_l[n][0], p1 = pi_l[n][1], p2 = pi_l[n][2], p3 = pi_l[n][3];
    bf16x8 o;
#pragma unroll
    for (int j = 0; j < 8; ++j)
      o[j] = (bf16)(p0*w[0][j] + p1*w[1][j] + p2*w[2][j] + p3*w[3][j]);
    *(bf16x8*)(wn + ((size_t)n*1152 + c*144 + kk*16 + cbg)*512 + lane*8) = o;
  }
}

// Conv (frozen R14): block = 8 rows x 64 co; 4 waves, wave wv owns rows h0+wv*2,
// h0+wv*2+1. Weights(c+1) global->VGPR during compute(c) (T14), ds_write at chunk
// boundary; x DMAs drain at barrier2. xs g-planes padded +16B -> distinct bank offsets.
#define XROWS 10
#define XW 66
#define XSG (XROWS*XW*8 + 8)  // 5288 el per g-plane
#define XS_E (4*XSG)          // 21152 el = 42304 B
#define WA_E (9*4*512)        // 18432 el = 36864 B

__global__ __launch_bounds__(256, 2)
void conv_kernel(const bf16* __restrict__ xb, const bf16* __restrict__ wn,
                 const float* __restrict__ pi, const float* __restrict__ Bbank,
                 float* __restrict__ y) {
  __shared__ __align__(16) bf16 xs[XS_E];
  __shared__ __align__(16) bf16 wa[WA_E];
  __shared__ float bns[64];
  const int tid = threadIdx.x;
  const int wv = tid >> 6, lane = tid & 63;
  const int l = lane & 15, u = lane >> 4;
  // XCD-aware swizzle (bijective, 1024 % 8 == 0): each XCD owns 4 consecutive n's.
  const int flat = blockIdx.x;
  const int wid = ((flat & 7) << 7) + (flat >> 3);
  const int n   = wid >> 5;
  const int hwb = (wid >> 2) & 7;
  const int cot = wid & 3;
  const int h0 = hwb * 8;

  const bf16* wnb = wn + (size_t)n*1152*512 + (size_t)(cot*4 + wv)*512 + lane*8;
  const bf16* xgb = xb + (size_t)n*32*4096*8 + lane*8;

  bf16x8 wstg[9];
  auto LOADW = [&](int c) {
    const bf16* seg = wnb + (size_t)c*144*512;
#pragma unroll
    for (int kk = 0; kk < 9; ++kk)
      wstg[kk] = *(const bf16x8*)(seg + (size_t)kk*16*512);
  };

  LOADW(0);                     // in flight under prologue

  // one-time zero: halo cols (wl=0,65) + OOB rows + pads stay zero forever
  for (int i = tid; i < XS_E/8; i += 256) ((int4*)xs)[i] = int4{0,0,0,0};
  if (tid < 64) {
    int co = cot*64 + tid;
    bns[tid] = pi[n*4+0]*Bbank[co*4+0] + pi[n*4+1]*Bbank[co*4+1]
             + pi[n*4+2]*Bbank[co*4+2] + pi[n*4+3]*Bbank[co*4+3];
  }

  f32x4 acc[2][4][4];
#pragma unroll
  for (int o = 0; o < 2; ++o)
#pragma unroll
    for (int a = 0; a < 4; ++a)
#pragma unroll
      for (int b = 0; b < 4; ++b)
#pragma unroll
        for (int k = 0; k < 4; ++k) acc[o][a][b][k] = 0.f;

  for (int c = 0; c < 8; ++c) {
    __syncthreads();            // all waves done reading xs/wa of chunk c-1
    {
      const bf16* xg = xgb + (size_t)(c*4 + wv)*4096*8;
#pragma unroll
      for (int r = 0; r < XROWS; ++r) {
        int hp = h0 - 1 + r;
        if (hp >= 0 && hp < HH)
          async16(&xs[wv*XSG + (r*XW + 1)*8], xg + (size_t)hp*64*8);
      }
    }
#pragma unroll
    for (int kk = 0; kk < 9; ++kk)
      *(int4*)(&wa[kk*2048 + wv*512 + lane*8]) = *(int4*)&wstg[kk];
    __syncthreads();            // vm (x DMA) + lgkm (wa writes) drained
    if (c < 7) LOADW(c + 1);    // weight latency hides under compute

    auto LD = [&](int rr, int f, int kx) {
      return *(const bf16x8*)(&xs[u*XSG + ((wv*2 + rr)*XW + f*16 + l + kx)*8]);
    };
    auto MM = [&](int ky, int kx, bf16x8 (&lo)[4], bf16x8 (&hi)[4]) {
      const int kk = ky*3 + kx;
      __builtin_amdgcn_s_setprio(1);
#pragma unroll
      for (int cb = 0; cb < 4; ++cb) {
        bf16x8 afr = *(const bf16x8*)(&wa[kk*2048 + cb*512 + lane*8]);
#pragma unroll
        for (int f = 0; f < 4; ++f) {
          acc[0][cb][f] = __builtin_amdgcn_mfma_f32_16x16x32_bf16(afr, lo[f], acc[0][cb][f], 0, 0, 0);
          acc[1][cb][f] = __builtin_amdgcn_mfma_f32_16x16x32_bf16(afr, hi[f], acc[1][cb][f], 0, 0, 0);
        }
      }
      __builtin_amdgcn_s_setprio(0);
    };
#pragma unroll
    for (int kx = 0; kx < 3; ++kx) {
      bf16x8 rA[4], rB[4];
#pragma unroll
      for (int f = 0; f < 4; ++f) { rA[f] = LD(0, f, kx); rB[f] = LD(1, f, kx); }
      MM(0, kx, rA, rB);        // ky=0: rows 0,1
#pragma unroll
      for (int f = 0; f < 4; ++f) rA[f] = LD(2, f, kx);
      MM(1, kx, rB, rA);        // ky=1: rows 1,2
#pragma unroll
      for (int f = 0; f < 4; ++f) rB[f] = LD(3, f, kx);
      MM(2, kx, rA, rB);        // ky=2: rows 2,3
    }
  }
  // epilogue: D row=(lane>>4)*4+reg -> co, col=lane&15 -> w
#pragma unroll
  for (int o = 0; o < 2; ++o) {
    const int h = h0 + wv*2 + o;
#pragma unroll
    for (int cb = 0; cb < 4; ++cb) {
#pragma unroll
      for (int f = 0; f < 4; ++f) {
        const int wcol = f*16 + l;
#pragma unroll
        for (int r4 = 0; r4 < 4; ++r4) {
          const int col = cb*16 + u*4 + r4;
          y[(((size_t)n*CO + cot*64 + col)*HH + h)*WW + wcol] = acc[o][cb][f][r4] + bns[col];
        }
      }
    }
  }
}

extern "C" void kernel_launch(void* const* d_in, const int* in_sizes, int n_in,
                              void* d_out, int out_size, void* d_ws, size_t ws_size,
                              hipStream_t stream) {
  const float* x     = (const float*)d_in[0];
  const float* Wbank = (const float*)d_in[1];
  const float* Bbank = (const float*)d_in[2];
  const float* w1    = (const float*)d_in[3];
  const float* b1    = (const float*)d_in[4];
  const float* w2    = (const float*)d_in[5];
  const float* b2    = (const float*)d_in[6];
  float* y = (float*)d_out;

  bf16*  wn     = (bf16*)d_ws;                                  // 37.75 MB
  bf16*  xb     = (bf16*)((char*)d_ws + WN_BYTES);              // 67.1 MB
  float* pooled = (float*)((char*)d_ws + WN_BYTES + XB_BYTES);  // 32 KB
  float* pi     = pooled + NB*CI;                               // 512 B

  dim3 cg(32, NB);
  cvt_pool_kernel<<<cg, 256, 0, stream>>>(x, xb, pooled);
  agg_kernel<<<288, 256, 0, stream>>>(Wbank, pooled, w1, b1, w2, b2, pi, wn);
  conv_kernel<<<1024, 256, 0, stream>>>(xb, wn, pi, Bbank, y);
}

// Round 16
// 189.056 us; speedup vs baseline: 1.6525x; 1.6525x over previous
//
#include <hip/hip_runtime.h>
#include <hip/hip_bf16.h>
#include <stdint.h>

typedef __bf16 bf16;
typedef __bf16 bf16x8 __attribute__((ext_vector_type(8)));
typedef float f32x4 __attribute__((ext_vector_type(4)));

#define TAU (1.0f/30.0f)

#define NB 32
#define CI 256
#define CO 256
#define HH 64
#define WW 64
#define HID 64

// wn fragment-linear layout: [n][c(8 ci-chunks)][kk(9)][cbg(16)][lane(64)][j(8)]
#define WN_ELEMS ((size_t)NB*8*9*16*512)
#define WN_BYTES (WN_ELEMS*2)
// xb packed layout: [n][cg(32 ci-groups of 8)][h(64)][w(64)][j(8)] bf16
#define XB_ELEMS ((size_t)NB*32*64*64*8)
#define XB_BYTES (XB_ELEMS*2)

__device__ __forceinline__ void async16(void* lds_uniform_base, const void* g_perlane) {
  __builtin_amdgcn_global_load_lds(
      (const __attribute__((address_space(1))) uint32_t*)g_perlane,
      (__attribute__((address_space(3))) uint32_t*)lds_uniform_base, 16, 0, 0);
}

// Fused fp32->bf16 repack + global average pool (scalar loads: BW-bound;
// R13 showed float4+select packing regresses VALU).
__global__ void cvt_pool_kernel(const float* __restrict__ x, bf16* __restrict__ xb,
                                float* __restrict__ pooled) {
  const int cg = blockIdx.x, n = blockIdx.y, tid = threadIdx.x;
  const float* base = x + ((size_t)n*CI + cg*8)*4096;
  bf16* ob = xb + ((size_t)n*32 + cg)*4096*8;
  float s[8];
#pragma unroll
  for (int j = 0; j < 8; ++j) s[j] = 0.f;
  for (int it = 0; it < 16; ++it) {
    int pos = it*256 + tid;
    bf16x8 o;
#pragma unroll
    for (int j = 0; j < 8; ++j) {
      float v = base[(size_t)j*4096 + pos];
      s[j] += v;
      o[j] = (bf16)v;
    }
    *(bf16x8*)(ob + (size_t)pos*8) = o;
  }
  __shared__ float red[4][8];
#pragma unroll
  for (int j = 0; j < 8; ++j)
#pragma unroll
    for (int off = 32; off; off >>= 1) s[j] += __shfl_xor(s[j], off);
  int wv = tid >> 6, lane = tid & 63;
  if (lane == 0)
#pragma unroll
    for (int j = 0; j < 8; ++j) red[wv][j] = s[j];
  __syncthreads();
  if (tid < 8) {
    float t = red[0][tid] + red[1][tid] + red[2][tid] + red[3][tid];
    pooled[n*CI + cg*8 + tid] = t * (1.0f/4096.0f);
  }
}

__global__ void attn_kernel(const float* __restrict__ pooled,
                            const float* __restrict__ w1, const float* __restrict__ b1,
                            const float* __restrict__ w2, const float* __restrict__ b2,
                            float* __restrict__ pi) {
  int n = blockIdx.x, h = threadIdx.x;        // 64 threads
  __shared__ float hm[HID];
  __shared__ float lgs[4];
  const float* pr = pooled + n*CI;
  float s = b1[h];
  for (int c = 0; c < CI; ++c) s += pr[c] * w1[h*CI + c];
  hm[h] = s > 0.f ? s : 0.f;
  __syncthreads();
  if (h < 4) {
    float lg = b2[h];
    for (int k = 0; k < HID; ++k) lg += hm[k] * w2[h*HID + k];
    lgs[h] = lg * TAU;
  }
  __syncthreads();
  if (h == 0) {
    float mx = fmaxf(fmaxf(lgs[0], lgs[1]), fmaxf(lgs[2], lgs[3]));
    float e0 = expf(lgs[0]-mx), e1 = expf(lgs[1]-mx), e2 = expf(lgs[2]-mx), e3 = expf(lgs[3]-mx);
    float inv = 1.f / (e0+e1+e2+e3);
    pi[n*4+0] = e0*inv; pi[n*4+1] = e1*inv; pi[n*4+2] = e2*inv; pi[n*4+3] = e3*inv;
  }
}

__global__ void agg_kernel(const float* __restrict__ Wbank, const float* __restrict__ pi,
                           bf16* __restrict__ wn) {
  int wid = blockIdx.x * 4 + (threadIdx.x >> 6);   // 0..1151
  int lane = threadIdx.x & 63;
  int c = wid / 144;
  int rem = wid - c*144;
  int kk = rem >> 4;
  int cbg = rem & 15;
  int co  = cbg*16 + (lane & 15);
  int ci0 = c*32 + (lane >> 4)*8;
  float w[4][8];
#pragma unroll
  for (int m = 0; m < 4; ++m)
#pragma unroll
    for (int j = 0; j < 8; ++j)
      w[m][j] = Wbank[(size_t)((co*4 + m)*256 + ci0 + j)*9 + kk];
  for (int n = 0; n < NB; ++n) {
    float p0 = pi[n*4+0], p1 = pi[n*4+1], p2 = pi[n*4+2], p3 = pi[n*4+3];
    bf16x8 o;
#pragma unroll
    for (int j = 0; j < 8; ++j)
      o[j] = (bf16)(p0*w[0][j] + p1*w[1][j] + p2*w[2][j] + p3*w[3][j]);
    *(bf16x8*)(wn + ((size_t)n*1152 + c*144 + kk*16 + cbg)*512 + lane*8) = o;
  }
}

// Conv (frozen R14): block = 8 rows x 64 co; 4 waves, wave wv owns rows h0+wv*2,
// h0+wv*2+1. Weights(c+1) global->VGPR during compute(c) (T14), ds_write at chunk
// boundary; x DMAs drain at barrier2. xs g-planes padded +16B -> distinct bank offsets.
#define XROWS 10
#define XW 66
#define XSG (XROWS*XW*8 + 8)  // 5288 el per g-plane
#define XS_E (4*XSG)          // 21152 el = 42304 B
#define WA_E (9*4*512)        // 18432 el = 36864 B

__global__ __launch_bounds__(256, 2)
void conv_kernel(const bf16* __restrict__ xb, const bf16* __restrict__ wn,
                 const float* __restrict__ pi, const float* __restrict__ Bbank,
                 float* __restrict__ y) {
  __shared__ __align__(16) bf16 xs[XS_E];
  __shared__ __align__(16) bf16 wa[WA_E];
  __shared__ float bns[64];
  const int tid = threadIdx.x;
  const int wv = tid >> 6, lane = tid & 63;
  const int l = lane & 15, u = lane >> 4;
  // XCD-aware swizzle (bijective, 1024 % 8 == 0): each XCD owns 4 consecutive n's.
  const int flat = blockIdx.x;
  const int wid = ((flat & 7) << 7) + (flat >> 3);
  const int n   = wid >> 5;
  const int hwb = (wid >> 2) & 7;
  const int cot = wid & 3;
  const int h0 = hwb * 8;

  const bf16* wnb = wn + (size_t)n*1152*512 + (size_t)(cot*4 + wv)*512 + lane*8;
  const bf16* xgb = xb + (size_t)n*32*4096*8 + lane*8;

  bf16x8 wstg[9];
  auto LOADW = [&](int c) {
    const bf16* seg = wnb + (size_t)c*144*512;
#pragma unroll
    for (int kk = 0; kk < 9; ++kk)
      wstg[kk] = *(const bf16x8*)(seg + (size_t)kk*16*512);
  };

  LOADW(0);                     // in flight under prologue

  // one-time zero: halo cols (wl=0,65) + OOB rows + pads stay zero forever
  for (int i = tid; i < XS_E/8; i += 256) ((int4*)xs)[i] = int4{0,0,0,0};
  if (tid < 64) {
    int co = cot*64 + tid;
    bns[tid] = pi[n*4+0]*Bbank[co*4+0] + pi[n*4+1]*Bbank[co*4+1]
             + pi[n*4+2]*Bbank[co*4+2] + pi[n*4+3]*Bbank[co*4+3];
  }

  f32x4 acc[2][4][4];
#pragma unroll
  for (int o = 0; o < 2; ++o)
#pragma unroll
    for (int a = 0; a < 4; ++a)
#pragma unroll
      for (int b = 0; b < 4; ++b)
#pragma unroll
        for (int k = 0; k < 4; ++k) acc[o][a][b][k] = 0.f;

  for (int c = 0; c < 8; ++c) {
    __syncthreads();            // all waves done reading xs/wa of chunk c-1
    {
      const bf16* xg = xgb + (size_t)(c*4 + wv)*4096*8;
#pragma unroll
      for (int r = 0; r < XROWS; ++r) {
        int hp = h0 - 1 + r;
        if (hp >= 0 && hp < HH)
          async16(&xs[wv*XSG + (r*XW + 1)*8], xg + (size_t)hp*64*8);
      }
    }
#pragma unroll
    for (int kk = 0; kk < 9; ++kk)
      *(int4*)(&wa[kk*2048 + wv*512 + lane*8]) = *(int4*)&wstg[kk];
    __syncthreads();            // vm (x DMA) + lgkm (wa writes) drained
    if (c < 7) LOADW(c + 1);    // weight latency hides under compute

    auto LD = [&](int rr, int f, int kx) {
      return *(const bf16x8*)(&xs[u*XSG + ((wv*2 + rr)*XW + f*16 + l + kx)*8]);
    };
    auto MM = [&](int ky, int kx, bf16x8 (&lo)[4], bf16x8 (&hi)[4]) {
      const int kk = ky*3 + kx;
      __builtin_amdgcn_s_setprio(1);
#pragma unroll
      for (int cb = 0; cb < 4; ++cb) {
        bf16x8 afr = *(const bf16x8*)(&wa[kk*2048 + cb*512 + lane*8]);
#pragma unroll
        for (int f = 0; f < 4; ++f) {
          acc[0][cb][f] = __builtin_amdgcn_mfma_f32_16x16x32_bf16(afr, lo[f], acc[0][cb][f], 0, 0, 0);
          acc[1][cb][f] = __builtin_amdgcn_mfma_f32_16x16x32_bf16(afr, hi[f], acc[1][cb][f], 0, 0, 0);
        }
      }
      __builtin_amdgcn_s_setprio(0);
    };
#pragma unroll
    for (int kx = 0; kx < 3; ++kx) {
      bf16x8 rA[4], rB[4];
#pragma unroll
      for (int f = 0; f < 4; ++f) { rA[f] = LD(0, f, kx); rB[f] = LD(1, f, kx); }
      MM(0, kx, rA, rB);        // ky=0: rows 0,1
#pragma unroll
      for (int f = 0; f < 4; ++f) rA[f] = LD(2, f, kx);
      MM(1, kx, rB, rA);        // ky=1: rows 1,2
#pragma unroll
      for (int f = 0; f < 4; ++f) rB[f] = LD(3, f, kx);
      MM(2, kx, rA, rB);        // ky=2: rows 2,3
    }
  }
  // epilogue: D row=(lane>>4)*4+reg -> co, col=lane&15 -> w
#pragma unroll
  for (int o = 0; o < 2; ++o) {
    const int h = h0 + wv*2 + o;
#pragma unroll
    for (int cb = 0; cb < 4; ++cb) {
#pragma unroll
      for (int f = 0; f < 4; ++f) {
        const int wcol = f*16 + l;
#pragma unroll
        for (int r4 = 0; r4 < 4; ++r4) {
          const int col = cb*16 + u*4 + r4;
          y[(((size_t)n*CO + cot*64 + col)*HH + h)*WW + wcol] = acc[o][cb][f][r4] + bns[col];
        }
      }
    }
  }
}

extern "C" void kernel_launch(void* const* d_in, const int* in_sizes, int n_in,
                              void* d_out, int out_size, void* d_ws, size_t ws_size,
                              hipStream_t stream) {
  const float* x     = (const float*)d_in[0];
  const float* Wbank = (const float*)d_in[1];
  const float* Bbank = (const float*)d_in[2];
  const float* w1    = (const float*)d_in[3];
  const float* b1    = (const float*)d_in[4];
  const float* w2    = (const float*)d_in[5];
  const float* b2    = (const float*)d_in[6];
  float* y = (float*)d_out;

  bf16*  wn     = (bf16*)d_ws;                                  // 37.75 MB
  bf16*  xb     = (bf16*)((char*)d_ws + WN_BYTES);              // 67.1 MB
  float* pooled = (float*)((char*)d_ws + WN_BYTES + XB_BYTES);  // 32 KB
  float* pi     = pooled + NB*CI;                               // 512 B

  dim3 cg(32, NB);
  cvt_pool_kernel<<<cg, 256, 0, stream>>>(x, xb, pooled);
  attn_kernel<<<NB, HID, 0, stream>>>(pooled, w1, b1, w2, b2, pi);
  agg_kernel<<<288, 256, 0, stream>>>(Wbank, pi, wn);
  conv_kernel<<<1024, 256, 0, stream>>>(xb, wn, pi, Bbank, y);
}